// Round 3
// baseline (332.613 us; speedup 1.0000x reference)
//
#include <hip/hip_runtime.h>
#include <math.h>

#define IN_C 64
#define HC 128      // H*OUT_C
#define NHEAD 4
#define EWD 16
#define NEG 0.2f

__device__ __forceinline__ float lrelu(float v) { return v > 0.f ? v : NEG * v; }

// ---------------------------------------------------------------- K1: h = x@W, a_src, a_dst
__global__ void k_feat(const float* __restrict__ x, const float* __restrict__ W,
                       const float* __restrict__ att_s, const float* __restrict__ att_d,
                       float* __restrict__ h, float* __restrict__ a_src, float* __restrict__ a_dst,
                       int N) {
    __shared__ float Ws[IN_C * HC];   // 32 KB
    __shared__ float xs[4][IN_C];
    const int tid = threadIdx.x;      // 128 threads
    {
        const float4* W4 = (const float4*)W;
        float4* Ws4 = (float4*)Ws;
#pragma unroll
        for (int i = 0; i < (IN_C * HC / 4) / 128; ++i)  // 16 iters
            Ws4[tid + i * 128] = W4[tid + i * 128];
    }
    const float as = att_s[tid];      // att_src flat[tid] == [head][c]
    const float ad = att_d[tid];
    const int head = tid >> 5;
    for (int base = blockIdx.x * 4; base < N; base += gridDim.x * 4) {
        const int nrows = min(4, N - base);
        __syncthreads();              // protect xs reuse (also orders Ws stores on 1st iter)
        if (tid < 64) {
            int r = tid >> 4, q = tid & 15;
            if (r < nrows)
                ((float4*)&xs[r][0])[q] = ((const float4*)(x + (size_t)(base + r) * IN_C))[q];
        }
        __syncthreads();
        for (int r = 0; r < nrows; ++r) {
            float acc = 0.f;
#pragma unroll
            for (int c = 0; c < IN_C; ++c)
                acc = fmaf(xs[r][c], Ws[c * HC + tid], acc);
            const int n = base + r;
            h[(size_t)n * HC + tid] = acc;
            float ps = acc * as, pd = acc * ad;
#pragma unroll
            for (int off = 16; off; off >>= 1) {
                ps += __shfl_xor(ps, off, 32);
                pd += __shfl_xor(pd, off, 32);
            }
            if ((tid & 31) == 0) {
                a_src[n * NHEAD + head] = ps;
                a_dst[n * NHEAD + head] = pd;
            }
        }
    }
}

// ---------------------------------------------------------------- degree histogram
__global__ void k_count(const int* __restrict__ dst, int* __restrict__ deg, int E) {
    int e = blockIdx.x * 256 + threadIdx.x;
    if (e < E) atomicAdd(&deg[dst[e]], 1);
}

// ---------------------------------------------------------------- 3-kernel exclusive scan (chunks of 1024)
__global__ void k_scan1(const int* __restrict__ deg, int* __restrict__ part, int N) {
    const int b = blockIdx.x, tid = threadIdx.x;  // 256
    int base = b * 1024 + tid * 4;
    int s = 0;
#pragma unroll
    for (int k = 0; k < 4; ++k) { int i = base + k; if (i < N) s += deg[i]; }
#pragma unroll
    for (int off = 32; off; off >>= 1) s += __shfl_xor(s, off, 64);
    __shared__ int ls[4];
    if ((tid & 63) == 0) ls[tid >> 6] = s;
    __syncthreads();
    if (tid == 0) part[b] = ls[0] + ls[1] + ls[2] + ls[3];
}

__global__ void k_scan2(int* part, int nb) {
    const int tid = threadIdx.x;  // 64, nb <= 64
    int orig = (tid < nb) ? part[tid] : 0;
    int v = orig;
#pragma unroll
    for (int off = 1; off < 64; off <<= 1) {
        int t = __shfl_up(v, off, 64);
        if (tid >= off) v += t;
    }
    if (tid < nb) part[tid] = v - orig;  // exclusive
}

__global__ void k_scan3(const int* __restrict__ deg, const int* __restrict__ part,
                        int* __restrict__ rowptr, int* __restrict__ cursor, int N, int E) {
    const int b = blockIdx.x, tid = threadIdx.x;  // 256
    int base = b * 1024 + tid * 4;
    int d[4]; int s = 0;
#pragma unroll
    for (int k = 0; k < 4; ++k) { int i = base + k; d[k] = (i < N) ? deg[i] : 0; s += d[k]; }
    int v = s;
#pragma unroll
    for (int off = 1; off < 64; off <<= 1) {
        int t = __shfl_up(v, off, 64);
        if ((tid & 63) >= off) v += t;
    }
    __shared__ int wsum[4];
    if ((tid & 63) == 63) wsum[tid >> 6] = v;
    __syncthreads();
    int waveoff = 0;
    const int w = tid >> 6;
    for (int k = 0; k < w; ++k) waveoff += wsum[k];
    int excl = v - s + waveoff + part[b];
#pragma unroll
    for (int k = 0; k < 4; ++k) {
        int i = base + k;
        if (i < N) { rowptr[i] = excl; cursor[i] = excl; }
        excl += d[k];
    }
    if (b == 0 && tid == 0) rowptr[N] = E;
}

// ---------------------------------------------------------------- fused: edge softmax + logits; ex coalesced, (src,eid) scattered
__global__ void k_fill(const int* __restrict__ src, const int* __restrict__ dst,
                       const float* __restrict__ ew, const float* __restrict__ Wl,
                       const float* __restrict__ bl,
                       const float* __restrict__ a_src, const float* __restrict__ a_dst,
                       int* __restrict__ cursor, int2* __restrict__ csr,
                       float4* __restrict__ ex_edge, float* __restrict__ partial, int E) {
    __shared__ float sW[EWD * NHEAD];
    __shared__ float sb[NHEAD];
    __shared__ float sred[4][4];
    const int tid = threadIdx.x;  // 256, one edge per thread
    if (tid < EWD * NHEAD) sW[tid] = Wl[tid];
    if (tid < NHEAD) sb[tid] = bl[tid];
    __syncthreads();
    float loc[4] = {0.f, 0.f, 0.f, 0.f};
    const int e = blockIdx.x * 256 + tid;
    if (e < E) {
        // edge_alpha = softmax(ew[e] @ Wl + bl) over heads
        const float4* w4 = (const float4*)(ew + (size_t)e * EWD);
        float v[4];
#pragma unroll
        for (int hh = 0; hh < 4; ++hh) v[hh] = sb[hh];
#pragma unroll
        for (int q = 0; q < 4; ++q) {
            float4 t = w4[q];
            float tv[4] = {t.x, t.y, t.z, t.w};
#pragma unroll
            for (int k = 0; k < 4; ++k)
#pragma unroll
                for (int hh = 0; hh < 4; ++hh)
                    v[hh] = fmaf(tv[k], sW[(q * 4 + k) * 4 + hh], v[hh]);
        }
        float m = fmaxf(fmaxf(v[0], v[1]), fmaxf(v[2], v[3]));
        float s = 0.f;
#pragma unroll
        for (int hh = 0; hh < 4; ++hh) { v[hh] = __expf(v[hh] - m); s += v[hh]; }
        float inv = 1.f / s;
#pragma unroll
        for (int hh = 0; hh < 4; ++hh) { v[hh] *= inv; loc[hh] += v[hh]; }
        // edge logits -> exp(lrelu(.))
        const int sn = src[e], dn = dst[e];
        float4 as = ((const float4*)a_src)[sn];
        float4 ad = ((const float4*)a_dst)[dn];
        float4 ex;
        ex.x = __expf(lrelu(as.x + ad.x + v[0]));
        ex.y = __expf(lrelu(as.y + ad.y + v[1]));
        ex.z = __expf(lrelu(as.z + ad.z + v[2]));
        ex.w = __expf(lrelu(as.w + ad.w + v[3]));
        ex_edge[e] = ex;                          // coalesced 16B
        int slot = atomicAdd(&cursor[dn], 1);
        csr[slot] = make_int2(sn, e);             // single scattered 8B
    }
    // block-level partial sums of edge_alpha (for self-loop mean)
    const int w = tid >> 6;
#pragma unroll
    for (int hh = 0; hh < 4; ++hh) {
        float v = loc[hh];
#pragma unroll
        for (int off = 32; off; off >>= 1) v += __shfl_xor(v, off, 64);
        if ((tid & 63) == 0) sred[w][hh] = v;
    }
    __syncthreads();
    if (tid < 4)
        partial[blockIdx.x * 4 + tid] =
            sred[0][tid] + sred[1][tid] + sred[2][tid] + sred[3][tid];
}

// ---------------------------------------------------------------- reduce partials -> asum[4]
__global__ void k_red(const float* __restrict__ partial, float* __restrict__ asum, int nb) {
    const int tid = threadIdx.x;  // 256: wave w handles head w
    const int w = tid >> 6, lane = tid & 63;
    float s = 0.f;
    for (int b = lane; b < nb; b += 64) s += partial[b * 4 + w];
#pragma unroll
    for (int off = 32; off; off >>= 1) s += __shfl_xor(s, off, 64);
    if (lane == 0) asum[w] = s;
}

// ---------------------------------------------------------------- aggregate: one block (128 thr) per dst node
__global__ void k_agg(const float* __restrict__ h, const int* __restrict__ rowptr,
                      const int2* __restrict__ csr, const float4* __restrict__ ex_edge,
                      const float* __restrict__ a_src, const float* __restrict__ a_dst,
                      const float* __restrict__ asum, const float* __restrict__ bias,
                      float* __restrict__ out, int N, int E) {
    const int d = blockIdx.x;
    const int tid = threadIdx.x;   // 128: one output channel each
    const int head = tid >> 5;
    __shared__ int ssrc[32];
    __shared__ float sex[32][4];
    const int r0 = rowptr[d], r1 = rowptr[d + 1];
    float acc = 0.f, den = 0.f;
    for (int base = r0; base < r1; base += 32) {
        const int cnt = min(32, r1 - base);
        __syncthreads();
        if (tid < cnt) {
            int2 ce = csr[base + tid];
            ssrc[tid] = ce.x;
            float4 e4 = ex_edge[ce.y];            // L2/L3 gather, overlapped across 32 lanes
            sex[tid][0] = e4.x; sex[tid][1] = e4.y; sex[tid][2] = e4.z; sex[tid][3] = e4.w;
        }
        __syncthreads();
        int k = 0;
        for (; k + 4 <= cnt; k += 4) {            // 4 independent h-gathers in flight
            const int s0 = ssrc[k], s1 = ssrc[k+1], s2 = ssrc[k+2], s3 = ssrc[k+3];
            const float e0 = sex[k][head], e1 = sex[k+1][head],
                        e2 = sex[k+2][head], e3 = sex[k+3][head];
            const float h0 = h[(size_t)s0 * HC + tid];
            const float h1 = h[(size_t)s1 * HC + tid];
            const float h2 = h[(size_t)s2 * HC + tid];
            const float h3 = h[(size_t)s3 * HC + tid];
            acc = fmaf(h0, e0, acc); den += e0;
            acc = fmaf(h1, e1, acc); den += e1;
            acc = fmaf(h2, e2, acc); den += e2;
            acc = fmaf(h3, e3, acc); den += e3;
        }
        for (; k < cnt; ++k) {
            const int s = ssrc[k];
            const float ex = sex[k][head];
            acc = fmaf(h[(size_t)s * HC + tid], ex, acc);
            den += ex;
        }
    }
    // self loop: ea = mean(edge_alpha), src = dst = d
    const float mean = asum[head] * (1.0f / (float)E);
    float l = lrelu(a_src[d * NHEAD + head] + a_dst[d * NHEAD + head] + mean);
    const float exl = __expf(l);
    acc = fmaf(h[(size_t)d * HC + tid], exl, acc);
    den += exl;
    out[(size_t)d * HC + tid] = acc / (den + 1e-16f) + bias[tid];
}

// ----------------------------------------------------------------
extern "C" void kernel_launch(void* const* d_in, const int* in_sizes, int n_in,
                              void* d_out, int out_size, void* d_ws, size_t ws_size,
                              hipStream_t stream) {
    const float* x     = (const float*)d_in[0];
    const int*   ei    = (const int*)d_in[1];
    const float* ew    = (const float*)d_in[2];
    const float* W     = (const float*)d_in[3];
    const float* bias  = (const float*)d_in[4];
    const float* att_s = (const float*)d_in[5];
    const float* att_d = (const float*)d_in[6];
    const float* Wl    = (const float*)d_in[7];
    const float* bl    = (const float*)d_in[8];
    const int N = in_sizes[0] / IN_C;
    const int E = in_sizes[1] / 2;
    const int* src = ei;
    const int* dst = ei + E;
    float* out = (float*)d_out;

    const int FILL_BLOCKS = (E + 255) / 256;   // 3125: one edge per thread

    float* ws = (float*)d_ws;
    size_t off = 0;
    float* h      = ws + off; off += (size_t)N * HC;     // 25.6 MB
    float* a_src  = ws + off; off += (size_t)N * NHEAD;
    float* a_dst  = ws + off; off += (size_t)N * NHEAD;
    int*   deg    = (int*)(ws + off); off += N;          // zeroed
    float* asum   = ws + off; off += 4;
    int*   part   = (int*)(ws + off); off += 64;
    int*   rowptr = (int*)(ws + off); off += (size_t)N + 4;
    int*   cursor = (int*)(ws + off); off += N;
    int2*  csr    = (int2*)(ws + off); off += (size_t)E * 2;       // 6.4 MB
    float4* ex_edge = (float4*)(ws + off); off += (size_t)E * 4;   // 12.8 MB
    float* partial= ws + off; off += (size_t)FILL_BLOCKS * 4;      // ~47 MB total

    hipMemsetAsync(deg, 0, (size_t)N * 4, stream);

    k_feat<<<2048, 128, 0, stream>>>(x, W, att_s, att_d, h, a_src, a_dst, N);
    k_count<<<(E + 255) / 256, 256, 0, stream>>>(dst, deg, E);
    const int nb = (N + 1023) / 1024;  // 49 <= 64
    k_scan1<<<nb, 256, 0, stream>>>(deg, part, N);
    k_scan2<<<1, 64, 0, stream>>>(part, nb);
    k_scan3<<<nb, 256, 0, stream>>>(deg, part, rowptr, cursor, N, E);
    k_fill<<<FILL_BLOCKS, 256, 0, stream>>>(src, dst, ew, Wl, bl, a_src, a_dst,
                                            cursor, csr, ex_edge, partial, E);
    k_red<<<1, 256, 0, stream>>>(partial, asum, FILL_BLOCKS);
    k_agg<<<N, 128, 0, stream>>>(h, rowptr, csr, ex_edge, a_src, a_dst,
                                 asum, bias, out, N, E);
}

// Round 4
// 300.845 us; speedup vs baseline: 1.1056x; 1.1056x over previous
//
#include <hip/hip_runtime.h>
#include <math.h>

#define IN_C 64
#define HC 128      // H*OUT_C
#define NHEAD 4
#define EWD 16
#define NEG 0.2f

__device__ __forceinline__ float lrelu(float v) { return v > 0.f ? v : NEG * v; }
// f32 -> bf16 (RNE)
__device__ __forceinline__ unsigned short f2b(float f) {
    unsigned int u = __float_as_uint(f);
    unsigned int r = ((u >> 16) & 1u) + 0x7fffu;
    return (unsigned short)((u + r) >> 16);
}
// bf16 bits -> f32
__device__ __forceinline__ float b2f(unsigned int lo16) {
    return __uint_as_float(lo16 << 16);
}

// ---------------------------------------------------------------- K1: h(bf16) = x@W, a_src, a_dst
__global__ void k_feat(const float* __restrict__ x, const float* __restrict__ W,
                       const float* __restrict__ att_s, const float* __restrict__ att_d,
                       unsigned short* __restrict__ h_bf, float* __restrict__ a_src,
                       float* __restrict__ a_dst, int N) {
    __shared__ float Ws[IN_C * HC];   // 32 KB
    __shared__ float xs[4][IN_C];
    const int tid = threadIdx.x;      // 128 threads
    {
        const float4* W4 = (const float4*)W;
        float4* Ws4 = (float4*)Ws;
#pragma unroll
        for (int i = 0; i < (IN_C * HC / 4) / 128; ++i)  // 16 iters
            Ws4[tid + i * 128] = W4[tid + i * 128];
    }
    const float as = att_s[tid];      // att_src flat[tid] == [head][c]
    const float ad = att_d[tid];
    const int head = tid >> 5;
    for (int base = blockIdx.x * 4; base < N; base += gridDim.x * 4) {
        const int nrows = min(4, N - base);
        __syncthreads();              // protect xs reuse (also orders Ws stores on 1st iter)
        if (tid < 64) {
            int r = tid >> 4, q = tid & 15;
            if (r < nrows)
                ((float4*)&xs[r][0])[q] = ((const float4*)(x + (size_t)(base + r) * IN_C))[q];
        }
        __syncthreads();
        for (int r = 0; r < nrows; ++r) {
            float acc = 0.f;
#pragma unroll
            for (int c = 0; c < IN_C; ++c)
                acc = fmaf(xs[r][c], Ws[c * HC + tid], acc);
            const int n = base + r;
            h_bf[(size_t)n * HC + tid] = f2b(acc);
            float ps = acc * as, pd = acc * ad;
#pragma unroll
            for (int off = 16; off; off >>= 1) {
                ps += __shfl_xor(ps, off, 32);
                pd += __shfl_xor(pd, off, 32);
            }
            if ((tid & 31) == 0) {
                a_src[n * NHEAD + head] = ps;
                a_dst[n * NHEAD + head] = pd;
            }
        }
    }
}

// ---------------------------------------------------------------- degree histogram
__global__ void k_count(const int* __restrict__ dst, int* __restrict__ deg, int E) {
    int e = blockIdx.x * 256 + threadIdx.x;
    if (e < E) atomicAdd(&deg[dst[e]], 1);
}

// ---------------------------------------------------------------- 3-kernel exclusive scan (chunks of 1024)
__global__ void k_scan1(const int* __restrict__ deg, int* __restrict__ part, int N) {
    const int b = blockIdx.x, tid = threadIdx.x;  // 256
    int base = b * 1024 + tid * 4;
    int s = 0;
#pragma unroll
    for (int k = 0; k < 4; ++k) { int i = base + k; if (i < N) s += deg[i]; }
#pragma unroll
    for (int off = 32; off; off >>= 1) s += __shfl_xor(s, off, 64);
    __shared__ int ls[4];
    if ((tid & 63) == 0) ls[tid >> 6] = s;
    __syncthreads();
    if (tid == 0) part[b] = ls[0] + ls[1] + ls[2] + ls[3];
}

__global__ void k_scan2(int* part, int nb) {
    const int tid = threadIdx.x;  // 64, nb <= 64
    int orig = (tid < nb) ? part[tid] : 0;
    int v = orig;
#pragma unroll
    for (int off = 1; off < 64; off <<= 1) {
        int t = __shfl_up(v, off, 64);
        if (tid >= off) v += t;
    }
    if (tid < nb) part[tid] = v - orig;  // exclusive
}

__global__ void k_scan3(const int* __restrict__ deg, const int* __restrict__ part,
                        int* __restrict__ rowptr, int* __restrict__ cursor, int N, int E) {
    const int b = blockIdx.x, tid = threadIdx.x;  // 256
    int base = b * 1024 + tid * 4;
    int d[4]; int s = 0;
#pragma unroll
    for (int k = 0; k < 4; ++k) { int i = base + k; d[k] = (i < N) ? deg[i] : 0; s += d[k]; }
    int v = s;
#pragma unroll
    for (int off = 1; off < 64; off <<= 1) {
        int t = __shfl_up(v, off, 64);
        if ((tid & 63) >= off) v += t;
    }
    __shared__ int wsum[4];
    if ((tid & 63) == 63) wsum[tid >> 6] = v;
    __syncthreads();
    int waveoff = 0;
    const int w = tid >> 6;
    for (int k = 0; k < w; ++k) waveoff += wsum[k];
    int excl = v - s + waveoff + part[b];
#pragma unroll
    for (int k = 0; k < 4; ++k) {
        int i = base + k;
        if (i < N) { rowptr[i] = excl; cursor[i] = excl; }
        excl += d[k];
    }
    if (b == 0 && tid == 0) rowptr[N] = E;
}

// ---------------------------------------------------------------- fused: edge softmax + logits; one 16B scattered record/edge
__global__ void k_fill(const int* __restrict__ src, const int* __restrict__ dst,
                       const float* __restrict__ ew, const float* __restrict__ Wl,
                       const float* __restrict__ bl,
                       const float* __restrict__ a_src, const float* __restrict__ a_dst,
                       int* __restrict__ cursor, uint4* __restrict__ csr,
                       float* __restrict__ partial, int E) {
    __shared__ float sW[EWD * NHEAD];
    __shared__ float sb[NHEAD];
    __shared__ float sred[4][4];
    const int tid = threadIdx.x;  // 256, one edge per thread
    if (tid < EWD * NHEAD) sW[tid] = Wl[tid];
    if (tid < NHEAD) sb[tid] = bl[tid];
    __syncthreads();
    float loc[4] = {0.f, 0.f, 0.f, 0.f};
    const int e = blockIdx.x * 256 + tid;
    if (e < E) {
        // edge_alpha = softmax(ew[e] @ Wl + bl) over heads
        const float4* w4 = (const float4*)(ew + (size_t)e * EWD);
        float v[4];
#pragma unroll
        for (int hh = 0; hh < 4; ++hh) v[hh] = sb[hh];
#pragma unroll
        for (int q = 0; q < 4; ++q) {
            float4 t = w4[q];
            float tv[4] = {t.x, t.y, t.z, t.w};
#pragma unroll
            for (int k = 0; k < 4; ++k)
#pragma unroll
                for (int hh = 0; hh < 4; ++hh)
                    v[hh] = fmaf(tv[k], sW[(q * 4 + k) * 4 + hh], v[hh]);
        }
        float m = fmaxf(fmaxf(v[0], v[1]), fmaxf(v[2], v[3]));
        float s = 0.f;
#pragma unroll
        for (int hh = 0; hh < 4; ++hh) { v[hh] = __expf(v[hh] - m); s += v[hh]; }
        float inv = 1.f / s;
#pragma unroll
        for (int hh = 0; hh < 4; ++hh) { v[hh] *= inv; loc[hh] += v[hh]; }
        // edge logits -> exp(lrelu(.)), packed record
        const int sn = src[e], dn = dst[e];
        float4 as = ((const float4*)a_src)[sn];
        float4 ad = ((const float4*)a_dst)[dn];
        unsigned int e0 = f2b(__expf(lrelu(as.x + ad.x + v[0])));
        unsigned int e1 = f2b(__expf(lrelu(as.y + ad.y + v[1])));
        unsigned int e2 = f2b(__expf(lrelu(as.z + ad.z + v[2])));
        unsigned int e3 = f2b(__expf(lrelu(as.w + ad.w + v[3])));
        uint4 rec;
        rec.x = (unsigned int)sn;
        rec.y = e0 | (e1 << 16);
        rec.z = e2 | (e3 << 16);
        rec.w = 0u;
        int slot = atomicAdd(&cursor[dn], 1);
        csr[slot] = rec;                          // single scattered 16B
    }
    // block-level partial sums of edge_alpha (for self-loop mean)
    const int w = tid >> 6;
#pragma unroll
    for (int hh = 0; hh < 4; ++hh) {
        float v = loc[hh];
#pragma unroll
        for (int off = 32; off; off >>= 1) v += __shfl_xor(v, off, 64);
        if ((tid & 63) == 0) sred[w][hh] = v;
    }
    __syncthreads();
    if (tid < 4)
        partial[blockIdx.x * 4 + tid] =
            sred[0][tid] + sred[1][tid] + sred[2][tid] + sred[3][tid];
}

// ---------------------------------------------------------------- reduce partials -> asum[4]
__global__ void k_red(const float* __restrict__ partial, float* __restrict__ asum, int nb) {
    const int tid = threadIdx.x;  // 256: wave w handles head w
    const int w = tid >> 6, lane = tid & 63;
    float s = 0.f;
    for (int b = lane; b < nb; b += 64) s += partial[b * 4 + w];
#pragma unroll
    for (int off = 32; off; off >>= 1) s += __shfl_xor(s, off, 64);
    if (lane == 0) asum[w] = s;
}

// ---------------------------------------------------------------- aggregate: one block (128 thr) per dst node
__global__ void k_agg(const unsigned short* __restrict__ h_bf, const int* __restrict__ rowptr,
                      const uint4* __restrict__ csr,
                      const float* __restrict__ a_src, const float* __restrict__ a_dst,
                      const float* __restrict__ asum, const float* __restrict__ bias,
                      float* __restrict__ out, int N, int E) {
    const int d = blockIdx.x;
    const int tid = threadIdx.x;   // 128: one output channel each
    const int head = tid >> 5;
    __shared__ int ssrc[32];
    __shared__ float sex[32][4];
    const int r0 = rowptr[d], r1 = rowptr[d + 1];
    float acc = 0.f, den = 0.f;
    for (int base = r0; base < r1; base += 32) {
        const int cnt = min(32, r1 - base);
        __syncthreads();
        if (tid < cnt) {
            uint4 rec = csr[base + tid];          // coalesced 16B, CSR-ordered
            ssrc[tid] = (int)rec.x;
            sex[tid][0] = b2f(rec.y & 0xffffu);
            sex[tid][1] = b2f(rec.y >> 16);
            sex[tid][2] = b2f(rec.z & 0xffffu);
            sex[tid][3] = b2f(rec.z >> 16);
        }
        __syncthreads();
        int k = 0;
        for (; k + 4 <= cnt; k += 4) {            // 4 independent h-gathers in flight
            const int s0 = ssrc[k], s1 = ssrc[k+1], s2 = ssrc[k+2], s3 = ssrc[k+3];
            const float e0 = sex[k][head], e1 = sex[k+1][head],
                        e2 = sex[k+2][head], e3 = sex[k+3][head];
            const float h0 = b2f(h_bf[(size_t)s0 * HC + tid]);
            const float h1 = b2f(h_bf[(size_t)s1 * HC + tid]);
            const float h2 = b2f(h_bf[(size_t)s2 * HC + tid]);
            const float h3 = b2f(h_bf[(size_t)s3 * HC + tid]);
            acc = fmaf(h0, e0, acc); den += e0;
            acc = fmaf(h1, e1, acc); den += e1;
            acc = fmaf(h2, e2, acc); den += e2;
            acc = fmaf(h3, e3, acc); den += e3;
        }
        for (; k < cnt; ++k) {
            const int s = ssrc[k];
            const float ex = sex[k][head];
            acc = fmaf(b2f(h_bf[(size_t)s * HC + tid]), ex, acc);
            den += ex;
        }
    }
    // self loop: ea = mean(edge_alpha), src = dst = d
    const float mean = asum[head] * (1.0f / (float)E);
    float l = lrelu(a_src[d * NHEAD + head] + a_dst[d * NHEAD + head] + mean);
    const float exl = __expf(l);
    acc = fmaf(b2f(h_bf[(size_t)d * HC + tid]), exl, acc);
    den += exl;
    out[(size_t)d * HC + tid] = acc / (den + 1e-16f) + bias[tid];
}

// ----------------------------------------------------------------
extern "C" void kernel_launch(void* const* d_in, const int* in_sizes, int n_in,
                              void* d_out, int out_size, void* d_ws, size_t ws_size,
                              hipStream_t stream) {
    const float* x     = (const float*)d_in[0];
    const int*   ei    = (const int*)d_in[1];
    const float* ew    = (const float*)d_in[2];
    const float* W     = (const float*)d_in[3];
    const float* bias  = (const float*)d_in[4];
    const float* att_s = (const float*)d_in[5];
    const float* att_d = (const float*)d_in[6];
    const float* Wl    = (const float*)d_in[7];
    const float* bl    = (const float*)d_in[8];
    const int N = in_sizes[0] / IN_C;
    const int E = in_sizes[1] / 2;
    const int* src = ei;
    const int* dst = ei + E;
    float* out = (float*)d_out;

    const int FILL_BLOCKS = (E + 255) / 256;   // 3125: one edge per thread

    float* ws = (float*)d_ws;
    size_t off = 0;
    unsigned short* h_bf = (unsigned short*)(ws + off); off += (size_t)N * HC / 2;  // 12.8 MB
    float* a_src  = ws + off; off += (size_t)N * NHEAD;
    float* a_dst  = ws + off; off += (size_t)N * NHEAD;
    int*   deg    = (int*)(ws + off); off += N;          // zeroed
    float* asum   = ws + off; off += 4;
    int*   part   = (int*)(ws + off); off += 64;
    int*   rowptr = (int*)(ws + off); off += (size_t)N + 4;
    int*   cursor = (int*)(ws + off); off += N;
    uint4* csr    = (uint4*)(ws + off); off += (size_t)E * 4;      // 12.8 MB
    float* partial= ws + off; off += (size_t)FILL_BLOCKS * 4;      // ~27 MB total

    hipMemsetAsync(deg, 0, (size_t)N * 4, stream);

    k_feat<<<2048, 128, 0, stream>>>(x, W, att_s, att_d, h_bf, a_src, a_dst, N);
    k_count<<<(E + 255) / 256, 256, 0, stream>>>(dst, deg, E);
    const int nb = (N + 1023) / 1024;  // 49 <= 64
    k_scan1<<<nb, 256, 0, stream>>>(deg, part, N);
    k_scan2<<<1, 64, 0, stream>>>(part, nb);
    k_scan3<<<nb, 256, 0, stream>>>(deg, part, rowptr, cursor, N, E);
    k_fill<<<FILL_BLOCKS, 256, 0, stream>>>(src, dst, ew, Wl, bl, a_src, a_dst,
                                            cursor, csr, partial, E);
    k_red<<<1, 256, 0, stream>>>(partial, asum, FILL_BLOCKS);
    k_agg<<<N, 128, 0, stream>>>(h_bf, rowptr, csr, a_src, a_dst,
                                 asum, bias, out, N, E);
}